// Round 1
// baseline (1221.641 us; speedup 1.0000x reference)
//
#include <hip/hip_runtime.h>

typedef unsigned short u16;
typedef unsigned int   u32;
typedef __bf16 bf16x8 __attribute__((ext_vector_type(8)));
typedef float  f32x4  __attribute__((ext_vector_type(4)));

__device__ __forceinline__ u16 f2bf(float f) {
  u32 u = __builtin_bit_cast(u32, f);
  u += 0x7FFFu + ((u >> 16) & 1u);   // RNE
  return (u16)(u >> 16);
}
__device__ __forceinline__ float bf2f(u16 v) {
  u32 u = ((u32)v) << 16;
  return __builtin_bit_cast(float, u);
}

#define GLDS16(g, l) __builtin_amdgcn_global_load_lds( \
    (const __attribute__((address_space(1))) void*)(g), \
    (__attribute__((address_space(3))) void*)(l), 16, 0, 0)

// ---------------- constants ----------------
#define DIMC   384
#define O3     1152
#define HWSZ   65536       // 256*256
#define NTOT   131072      // 2*HWSZ
#define NHEADS 8

// ---------------- K0a: weight prep ----------------
// wq_perm[o'][k] (o' = h*144 + z*48 + c), wp[o][c], zero scratch page
__global__ void k_prep(const float* __restrict__ qkv_w, const float* __restrict__ proj_w,
                       u16* __restrict__ wq, u16* __restrict__ wp, u16* __restrict__ zp) {
  int idx = blockIdx.x * 256 + threadIdx.x;
  if (idx < O3 * DIMC) {
    int op = idx / DIMC, k = idx - op * DIMC;
    int h = op / 144, rr = op - h * 144, z = rr / 48, c = rr - z * 48;
    int o = z * DIMC + h * 48 + c;
    wq[idx] = f2bf(qkv_w[(size_t)o * DIMC + k]);
  }
  if (idx < DIMC * DIMC) wp[idx] = f2bf(proj_w[idx]);
  if (idx < 128) zp[idx] = 0;
}

// ---------------- K0b: transpose x [b][c][hw] f32 -> xT [b*hw][c] bf16 ----------------
__global__ __launch_bounds__(256) void k_xpose(const float* __restrict__ x, u16* __restrict__ xT) {
  __shared__ u16 tile[64 * 66];   // 66 = odd-word stride -> conflict-free both sides
  int hw0 = blockIdx.x * 64;
  int c0  = blockIdx.y * 64;
  int b   = blockIdx.z;
  int t = threadIdx.x;
  int tx = t & 63, ty = t >> 6;
#pragma unroll
  for (int i = 0; i < 16; ++i) {
    int cl = ty + i * 4;
    float v = x[(size_t)(b * DIMC + c0 + cl) * HWSZ + hw0 + tx];
    tile[cl * 66 + tx] = f2bf(v);
  }
  __syncthreads();
  int hwl = t >> 2, cp = (t & 3) * 16;
  alignas(16) u16 tmp[16];
#pragma unroll
  for (int j = 0; j < 16; ++j) tmp[j] = tile[(cp + j) * 66 + hwl];
  size_t n = (size_t)(b << 16) + hw0 + hwl;
  u16* dst = xT + n * DIMC + c0 + cp;
  *(uint4*)(dst)     = *(const uint4*)(tmp);
  *(uint4*)(dst + 8) = *(const uint4*)(tmp + 8);
}

// ---------------- K1: qkvT[n][o'] = xT[n][k] * wq[o'][k]  (gemm-BT, bf16 MFMA) ----------------
__global__ __launch_bounds__(256, 3) void k_gemm_qkv(
    const u16* __restrict__ xT, const u16* __restrict__ wq, u16* __restrict__ qkvT) {
  __shared__ alignas(16) u16 As[128 * 32];
  __shared__ alignas(16) u16 Bs[128 * 32];
  const int t = threadIdx.x;
  const int m0 = blockIdx.y * 128;   // spatial
  const int n0 = blockIdx.x * 128;   // o'
  const int wave = t >> 6, lane = t & 63;
  const int wy = wave >> 1, wx = wave & 1;
  const int lm = lane & 15, lq = lane >> 4;

  f32x4 acc[4][4];
#pragma unroll
  for (int i = 0; i < 4; ++i)
#pragma unroll
    for (int j = 0; j < 4; ++j) acc[i][j] = (f32x4){0.f, 0.f, 0.f, 0.f};

  for (int kt = 0; kt < DIMC / 32; ++kt) {
#pragma unroll
    for (int s = 0; s < 2; ++s) {
      int ci = t + s * 256;
      int row = ci >> 2, kc = ci & 3;
      const u16* ga = xT + (size_t)(m0 + row) * DIMC + kt * 32 + kc * 8;
      const u16* gb = wq + (size_t)(n0 + row) * DIMC + kt * 32 + kc * 8;
      GLDS16(ga, &As[ci * 8]);
      GLDS16(gb, &Bs[ci * 8]);
    }
    __syncthreads();
    bf16x8 af[4], bf[4];
#pragma unroll
    for (int i = 0; i < 4; ++i) af[i] = *(const bf16x8*)&As[(wy * 64 + i * 16 + lm) * 32 + lq * 8];
#pragma unroll
    for (int j = 0; j < 4; ++j) bf[j] = *(const bf16x8*)&Bs[(wx * 64 + j * 16 + lm) * 32 + lq * 8];
#pragma unroll
    for (int i = 0; i < 4; ++i)
#pragma unroll
      for (int j = 0; j < 4; ++j)
        acc[i][j] = __builtin_amdgcn_mfma_f32_16x16x32_bf16(af[i], bf[j], acc[i][j], 0, 0, 0);
    __syncthreads();
  }
#pragma unroll
  for (int i = 0; i < 4; ++i) {
    int row_b = m0 + wy * 64 + i * 16 + lq * 4;
#pragma unroll
    for (int j = 0; j < 4; ++j) {
      int col = n0 + wx * 64 + j * 16 + lm;
#pragma unroll
      for (int r = 0; r < 4; ++r)
        qkvT[(size_t)(row_b + r) * O3 + col] = f2bf(acc[i][j][r]);
    }
  }
}

// ---------------- K2: fused dwconv + windowed channel attention ----------------
// grid: 2048 blocks = (b, wy, wx); 256 threads; 8 heads sequential per block.
__global__ __launch_bounds__(256, 2) void k_attn(
    const u16* __restrict__ qkvT, const float* __restrict__ dwg,
    const float* __restrict__ temperature, u16* __restrict__ aT,
    const u16* __restrict__ zp) {
  __shared__ alignas(16) u16 stage[14400];   // [100 pos][144 ch]; S & Ps alias this (dead after dwconv)
  __shared__ float dww[1296];                // [9 tap][144 ch]
  __shared__ alignas(16) u16 qs[48 * 72];
  __shared__ alignas(16) u16 ks2[48 * 72];
  __shared__ alignas(16) u16 vts[64 * 72];   // v^T [p][d], cols 48..63 zeroed
  __shared__ float norms[96];
  float* S  = (float*)stage;                 // [48][52] fp32 logits (9984 B)
  u16*  Ps  = stage + 4992;                  // [48][72] bf16 probs

  const int t = threadIdx.x;
  const int bi = blockIdx.x;
  const int b = bi >> 10;
  const int wid = bi & 1023;
  const int wy = wid >> 5, wx = wid & 31;
  const int y0 = wy * 8, x0 = wx * 8;
  const int wave = t >> 6, lane = t & 63, lm = lane & 15, lq = lane >> 4;

  for (int h = 0; h < NHEADS; ++h) {
    // phase 1: depthwise weights -> LDS (tap-major for conflict-free reads)
    for (int idx = t; idx < 1296; idx += 256) {
      int tap = idx / 144, ch = idx - tap * 144;
      int z = ch / 48, c = ch - z * 48;
      dww[tap * 144 + ch] = dwg[(size_t)(z * DIMC + h * 48 + c) * 9 + tap];
    }
    // phase 2: async halo stage: 100 pos x 144 ch bf16 = 1800 x 16B chunks
    for (int s = 0; s < 8; ++s) {
      int ci = t + s * 256;
      if (ci < 1800) {
        int pos = ci / 18, kc = ci - pos * 18;
        int dy = pos / 10, dx = pos - dy * 10;
        int y = y0 - 1 + dy, x = x0 - 1 + dx;
        const u16* ga;
        if ((unsigned)y < 256u && (unsigned)x < 256u)
          ga = qkvT + (size_t)((b << 16) + (y << 8) + x) * O3 + h * 144 + kc * 8;
        else
          ga = zp;   // zero page for padding
        GLDS16(ga, &stage[ci * 8]);
      }
    }
    __syncthreads();

    // phase 4: dwconv 3x3 (rolling window), thread t<144 owns channel ch
    if (t < 144) {
      int ch = t, z = ch / 48, c = ch - z * 48;
      float wv[9];
#pragma unroll
      for (int k9 = 0; k9 < 9; ++k9) wv[k9] = dww[k9 * 144 + ch];
      float sumsq = 0.f;
      for (int py = 0; py < 8; ++py) {
        int base = py * 1440 + ch;
        float a0 = bf2f(stage[base]),        a1 = bf2f(stage[base + 144]);
        float b0 = bf2f(stage[base + 1440]), b1 = bf2f(stage[base + 1584]);
        float c0 = bf2f(stage[base + 2880]), c1 = bf2f(stage[base + 3024]);
#pragma unroll
        for (int px = 0; px < 8; ++px) {
          float a2 = bf2f(stage[base + (px + 2) * 144]);
          float b2 = bf2f(stage[base + 1440 + (px + 2) * 144]);
          float c2 = bf2f(stage[base + 2880 + (px + 2) * 144]);
          float o = a0 * wv[0] + a1 * wv[1] + a2 * wv[2]
                  + b0 * wv[3] + b1 * wv[4] + b2 * wv[5]
                  + c0 * wv[6] + c1 * wv[7] + c2 * wv[8];
          int p = py * 8 + px;
          if (z == 0)      { qs[c * 72 + p] = f2bf(o); sumsq += o * o; }
          else if (z == 1) { ks2[c * 72 + p] = f2bf(o); sumsq += o * o; }
          else             { vts[p * 72 + c] = f2bf(o); }
          a0 = a1; a1 = a2; b0 = b1; b1 = b2; c0 = c1; c1 = c2;
        }
      }
      if (z < 2) norms[z * 48 + c] = 1.0f / fmaxf(sqrtf(sumsq), 1e-12f);
    }
    if (t < 64) {
#pragma unroll
      for (int d = 48; d < 64; ++d) vts[t * 72 + d] = 0;  // zero K-pad
    }
    __syncthreads();

    // phase 6: l2norm scaling of q,k
    for (int idx = t; idx < 6144; idx += 256) {
      if (idx < 3072) {
        int row = idx >> 6, p = idx & 63;
        qs[row * 72 + p] = f2bf(bf2f(qs[row * 72 + p]) * norms[row]);
      } else {
        int i2 = idx - 3072;
        int row = i2 >> 6, p = i2 & 63;
        ks2[row * 72 + p] = f2bf(bf2f(ks2[row * 72 + p]) * norms[48 + row]);
      }
    }
    __syncthreads();

    // phase 8: S = (q_hat k_hat^T) * temp   [48x48], waves 0..2
    float temp = temperature[h];
    if (wave < 3) {
      f32x4 acc3[3];
#pragma unroll
      for (int j = 0; j < 3; ++j) acc3[j] = (f32x4){0.f, 0.f, 0.f, 0.f};
#pragma unroll
      for (int ks_ = 0; ks_ < 2; ++ks_) {
        bf16x8 aq = *(const bf16x8*)&qs[(wave * 16 + lm) * 72 + ks_ * 32 + lq * 8];
#pragma unroll
        for (int j = 0; j < 3; ++j) {
          bf16x8 bk = *(const bf16x8*)&ks2[(j * 16 + lm) * 72 + ks_ * 32 + lq * 8];
          acc3[j] = __builtin_amdgcn_mfma_f32_16x16x32_bf16(aq, bk, acc3[j], 0, 0, 0);
        }
      }
#pragma unroll
      for (int j = 0; j < 3; ++j)
#pragma unroll
        for (int r = 0; r < 4; ++r)
          S[(wave * 16 + lq * 4 + r) * 52 + j * 16 + lm] = acc3[j][r] * temp;
    }
    __syncthreads();

    // phase 10: softmax rows (48), one wave-row at a time
    for (int i = 0; i < 12; ++i) {
      int row = wave * 12 + i;
      float v = (lane < 48) ? S[row * 52 + lane] : -1e30f;
      float mx = v;
#pragma unroll
      for (int off = 32; off; off >>= 1) mx = fmaxf(mx, __shfl_xor(mx, off));
      float e = (lane < 48) ? __expf(v - mx) : 0.f;
      float sm = e;
#pragma unroll
      for (int off = 32; off; off >>= 1) sm += __shfl_xor(sm, off);
      Ps[row * 72 + lane] = f2bf(e / sm);   // lanes 48..63 write 0 -> K-pad
    }
    __syncthreads();

    // phase 12: out^T[p][c] = v^T P^T  [64x48], all 4 waves
    {
      f32x4 accp[3];
#pragma unroll
      for (int j = 0; j < 3; ++j) accp[j] = (f32x4){0.f, 0.f, 0.f, 0.f};
#pragma unroll
      for (int ks_ = 0; ks_ < 2; ++ks_) {
        bf16x8 av = *(const bf16x8*)&vts[(wave * 16 + lm) * 72 + ks_ * 32 + lq * 8];
#pragma unroll
        for (int j = 0; j < 3; ++j) {
          bf16x8 bp = *(const bf16x8*)&Ps[(j * 16 + lm) * 72 + ks_ * 32 + lq * 8];
          accp[j] = __builtin_amdgcn_mfma_f32_16x16x32_bf16(av, bp, accp[j], 0, 0, 0);
        }
      }
#pragma unroll
      for (int j = 0; j < 3; ++j) {
#pragma unroll
        for (int r = 0; r < 4; ++r) {
          int p = wave * 16 + lq * 4 + r;
          int col = j * 16 + lm;
          int y = y0 + (p >> 3), x = x0 + (p & 7);
          size_t n = (size_t)((b << 16) + (y << 8) + x);
          aT[n * DIMC + h * 48 + col] = f2bf(accp[j][r]);
        }
      }
    }
    __syncthreads();   // protect Ps/vts before next head's staging
  }
}

// ---------------- K3: out[o][n] = wp[o][k] * aT[n][k] + bias[o]  (fp32 out) ----------------
__global__ __launch_bounds__(256, 3) void k_gemm_proj(
    const u16* __restrict__ wp, const u16* __restrict__ aT,
    const float* __restrict__ bias, float* __restrict__ out) {
  __shared__ alignas(16) u16 As[128 * 32];
  __shared__ alignas(16) u16 Bs[128 * 32];
  const int t = threadIdx.x;
  const int m0 = blockIdx.x * 128;   // o
  const int n0 = blockIdx.y * 128;   // spatial
  const int wave = t >> 6, lane = t & 63;
  const int wy = wave >> 1, wx = wave & 1;
  const int lm = lane & 15, lq = lane >> 4;

  f32x4 acc[4][4];
#pragma unroll
  for (int i = 0; i < 4; ++i)
#pragma unroll
    for (int j = 0; j < 4; ++j) acc[i][j] = (f32x4){0.f, 0.f, 0.f, 0.f};

  for (int kt = 0; kt < DIMC / 32; ++kt) {
#pragma unroll
    for (int s = 0; s < 2; ++s) {
      int ci = t + s * 256;
      int row = ci >> 2, kc = ci & 3;
      const u16* ga = wp + (size_t)(m0 + row) * DIMC + kt * 32 + kc * 8;
      const u16* gb = aT + (size_t)(n0 + row) * DIMC + kt * 32 + kc * 8;
      GLDS16(ga, &As[ci * 8]);
      GLDS16(gb, &Bs[ci * 8]);
    }
    __syncthreads();
    bf16x8 af[4], bf[4];
#pragma unroll
    for (int i = 0; i < 4; ++i) af[i] = *(const bf16x8*)&As[(wy * 64 + i * 16 + lm) * 32 + lq * 8];
#pragma unroll
    for (int j = 0; j < 4; ++j) bf[j] = *(const bf16x8*)&Bs[(wx * 64 + j * 16 + lm) * 32 + lq * 8];
#pragma unroll
    for (int i = 0; i < 4; ++i)
#pragma unroll
      for (int j = 0; j < 4; ++j)
        acc[i][j] = __builtin_amdgcn_mfma_f32_16x16x32_bf16(af[i], bf[j], acc[i][j], 0, 0, 0);
    __syncthreads();
  }
#pragma unroll
  for (int i = 0; i < 4; ++i) {
    int o_b = m0 + wy * 64 + i * 16 + lq * 4;
    float bi4[4];
#pragma unroll
    for (int r = 0; r < 4; ++r) bi4[r] = bias[o_b + r];
#pragma unroll
    for (int j = 0; j < 4; ++j) {
      int nsp = n0 + wx * 64 + j * 16 + lm;
      int b = nsp >> 16, hw = nsp & 0xFFFF;
#pragma unroll
      for (int r = 0; r < 4; ++r)
        out[(size_t)(b * DIMC + o_b + r) * HWSZ + hw] = acc[i][j][r] + bi4[r];
    }
  }
}

// ---------------- host ----------------
extern "C" void kernel_launch(void* const* d_in, const int* in_sizes, int n_in,
                              void* d_out, int out_size, void* d_ws, size_t ws_size,
                              hipStream_t stream) {
  const float* x    = (const float*)d_in[0];
  const float* qkvw = (const float*)d_in[1];
  const float* dwg  = (const float*)d_in[2];
  const float* temp = (const float*)d_in[3];
  const float* pw   = (const float*)d_in[4];
  const float* pb   = (const float*)d_in[5];
  float* out = (float*)d_out;

  char* w = (char*)d_ws;
  const size_t offXT = 0;                          // xT bf16 [131072][384] (later reused as attnOutT)
  const size_t offQK = offXT + (size_t)NTOT * DIMC * 2;   // qkvT bf16 [131072][1152]
  const size_t offWQ = offQK + (size_t)NTOT * O3 * 2;
  const size_t offWP = offWQ + (size_t)O3 * DIMC * 2;
  const size_t offZP = offWP + (size_t)DIMC * DIMC * 2;
  const size_t need  = offZP + 256;
  if (ws_size < need) return;   // ws too small -> output stays zero (diagnostic)

  u16* xT   = (u16*)(w + offXT);
  u16* qkvT = (u16*)(w + offQK);
  u16* wq   = (u16*)(w + offWQ);
  u16* wp   = (u16*)(w + offWP);
  u16* zp   = (u16*)(w + offZP);
  u16* aT   = xT;   // alias: xT is dead once k_gemm_qkv completes

  k_prep<<<dim3(1728), dim3(256), 0, stream>>>(qkvw, pw, wq, wp, zp);
  k_xpose<<<dim3(1024, 6, 2), dim3(256), 0, stream>>>(x, xT);
  k_gemm_qkv<<<dim3(9, 1024), dim3(256), 0, stream>>>(xT, wq, qkvT);
  k_attn<<<dim3(2048), dim3(256), 0, stream>>>(qkvT, dwg, temp, aT, zp);
  k_gemm_proj<<<dim3(3, 1024), dim3(256), 0, stream>>>(wp, aT, pb, out);
}

// Round 2
// 929.741 us; speedup vs baseline: 1.3140x; 1.3140x over previous
//
#include <hip/hip_runtime.h>

typedef unsigned short u16;
typedef unsigned int   u32;
typedef __bf16 bf16x8 __attribute__((ext_vector_type(8)));
typedef float  f32x4  __attribute__((ext_vector_type(4)));

__device__ __forceinline__ u16 f2bf(float f) {
  u32 u = __builtin_bit_cast(u32, f);
  u += 0x7FFFu + ((u >> 16) & 1u);   // RNE
  return (u16)(u >> 16);
}
__device__ __forceinline__ float bf2f(u16 v) {
  u32 u = ((u32)v) << 16;
  return __builtin_bit_cast(float, u);
}

#define GLDS16(g, l) __builtin_amdgcn_global_load_lds( \
    (const __attribute__((address_space(1))) void*)(g), \
    (__attribute__((address_space(3))) void*)(l), 16, 0, 0)

// ---------------- constants ----------------
#define DIMC   384
#define O3     1152
#define HWSZ   65536       // 256*256
#define NTOT   131072      // 2*HWSZ
#define NHEADS 8

// ---------------- K0a: weight prep ----------------
__global__ void k_prep(const float* __restrict__ qkv_w, const float* __restrict__ proj_w,
                       u16* __restrict__ wq, u16* __restrict__ wp, u16* __restrict__ zp) {
  int idx = blockIdx.x * 256 + threadIdx.x;
  if (idx < O3 * DIMC) {
    int op = idx / DIMC, k = idx - op * DIMC;
    int h = op / 144, rr = op - h * 144, z = rr / 48, c = rr - z * 48;
    int o = z * DIMC + h * 48 + c;
    wq[idx] = f2bf(qkv_w[(size_t)o * DIMC + k]);
  }
  if (idx < DIMC * DIMC) wp[idx] = f2bf(proj_w[idx]);
  if (idx < 128) zp[idx] = 0;
}

// ---------------- K0b: transpose x [b][c][hw] f32 -> xT [b*hw][c] bf16 ----------------
__global__ __launch_bounds__(256) void k_xpose(const float* __restrict__ x, u16* __restrict__ xT) {
  __shared__ u16 tile[64 * 66];
  int hw0 = blockIdx.x * 64;
  int c0  = blockIdx.y * 64;
  int b   = blockIdx.z;
  int t = threadIdx.x;
  int tx = t & 63, ty = t >> 6;
#pragma unroll
  for (int i = 0; i < 16; ++i) {
    int cl = ty + i * 4;
    float v = x[(size_t)(b * DIMC + c0 + cl) * HWSZ + hw0 + tx];
    tile[cl * 66 + tx] = f2bf(v);
  }
  __syncthreads();
  int hwl = t >> 2, cp = (t & 3) * 16;
  alignas(16) u16 tmp[16];
#pragma unroll
  for (int j = 0; j < 16; ++j) tmp[j] = tile[(cp + j) * 66 + hwl];
  size_t n = (size_t)(b << 16) + hw0 + hwl;
  u16* dst = xT + n * DIMC + c0 + cp;
  *(uint4*)(dst)     = *(const uint4*)(tmp);
  *(uint4*)(dst + 8) = *(const uint4*)(tmp + 8);
}

// ---------------- K1: qkvT[n][o'] = xT[n][k] * wq[o'][k]  (gemm-BT, bf16 MFMA) ----------------
__global__ __launch_bounds__(256, 3) void k_gemm_qkv(
    const u16* __restrict__ xT, const u16* __restrict__ wq, u16* __restrict__ qkvT) {
  __shared__ alignas(16) u16 As[128 * 32];
  __shared__ alignas(16) u16 Bs[128 * 32];
  const int t = threadIdx.x;
  const int m0 = blockIdx.y * 128;
  const int n0 = blockIdx.x * 128;
  const int wave = t >> 6, lane = t & 63;
  const int wy = wave >> 1, wx = wave & 1;
  const int lm = lane & 15, lq = lane >> 4;

  f32x4 acc[4][4];
#pragma unroll
  for (int i = 0; i < 4; ++i)
#pragma unroll
    for (int j = 0; j < 4; ++j) acc[i][j] = (f32x4){0.f, 0.f, 0.f, 0.f};

  for (int kt = 0; kt < DIMC / 32; ++kt) {
#pragma unroll
    for (int s = 0; s < 2; ++s) {
      int ci = t + s * 256;
      int row = ci >> 2, kc = ci & 3;
      const u16* ga = xT + (size_t)(m0 + row) * DIMC + kt * 32 + kc * 8;
      const u16* gb = wq + (size_t)(n0 + row) * DIMC + kt * 32 + kc * 8;
      GLDS16(ga, &As[ci * 8]);
      GLDS16(gb, &Bs[ci * 8]);
    }
    __syncthreads();
    bf16x8 af[4], bf[4];
#pragma unroll
    for (int i = 0; i < 4; ++i) af[i] = *(const bf16x8*)&As[(wy * 64 + i * 16 + lm) * 32 + lq * 8];
#pragma unroll
    for (int j = 0; j < 4; ++j) bf[j] = *(const bf16x8*)&Bs[(wx * 64 + j * 16 + lm) * 32 + lq * 8];
#pragma unroll
    for (int i = 0; i < 4; ++i)
#pragma unroll
      for (int j = 0; j < 4; ++j)
        acc[i][j] = __builtin_amdgcn_mfma_f32_16x16x32_bf16(af[i], bf[j], acc[i][j], 0, 0, 0);
    __syncthreads();
  }
#pragma unroll
  for (int i = 0; i < 4; ++i) {
    int row_b = m0 + wy * 64 + i * 16 + lq * 4;
#pragma unroll
    for (int j = 0; j < 4; ++j) {
      int col = n0 + wx * 64 + j * 16 + lm;
#pragma unroll
      for (int r = 0; r < 4; ++r)
        qkvT[(size_t)(row_b + r) * O3 + col] = f2bf(acc[i][j][r]);
    }
  }
}

// ---------------- K2: fused dwconv + windowed channel attention (v2) ----------------
// grid: (2048 windows, 8 heads); 256 threads; ONE (window, head) per block.
// LDS: stage 28800B [100 pos][144 ch] (S fp32[48][52] and P bf16[48][72] alias it),
//      qs 6912B [48 c][72 p], ks 6912B, vts 9216B [64 p][72 d]  => 51840B -> 3 blk/CU.
__global__ __launch_bounds__(256, 3) void k_attn(
    const u16* __restrict__ qkvT, const float* __restrict__ dwg,
    const float* __restrict__ temperature, u16* __restrict__ aT,
    const u16* __restrict__ zp) {
  __shared__ alignas(16) u16 stage[14400];   // 28800 B
  __shared__ alignas(16) u16 qs[48 * 72];
  __shared__ alignas(16) u16 ks2[48 * 72];
  __shared__ alignas(16) u16 vts[64 * 72];
  float* S = (float*)stage;                  // [48][52] fp32, bytes 0..9983
  u16*  Ps = stage + 6144;                   // [48][72] bf16, bytes 12288..19199

  const int t = threadIdx.x;
  const int wid = blockIdx.x;                // 0..2047
  const int h = blockIdx.y;                  // 0..7
  const int b = wid >> 10;
  const int w1 = wid & 1023;
  const int wy = w1 >> 5, wx = w1 & 31;
  const int y0 = wy * 8, x0 = wx * 8;
  const int wave = t >> 6, lane = t & 63, lm = lane & 15, lq = lane >> 4;

  // ---- preload dw weights for first task (overlaps with GLDS staging) ----
  float wv[9][4];
  {
    int quad = t >> 3;                        // 0..31 (first pass)
    int z = quad / 12, qc = quad - z * 12;
    int cb = z * DIMC + h * 48 + qc * 4;
#pragma unroll
    for (int cc = 0; cc < 4; ++cc)
#pragma unroll
      for (int tap = 0; tap < 9; ++tap)
        wv[tap][cc] = dwg[(size_t)(cb + cc) * 9 + tap];
  }

  // ---- async halo stage: 100 pos x 144 ch bf16 = 1800 x 16B chunks ----
#pragma unroll
  for (int s = 0; s < 8; ++s) {
    int ci = t + s * 256;
    if (ci < 1800) {
      int pos = ci / 18, kc = ci - pos * 18;
      int dy = pos / 10, dx = pos - dy * 10;
      int y = y0 - 1 + dy, x = x0 - 1 + dx;
      const u16* ga;
      if ((unsigned)y < 256u && (unsigned)x < 256u)
        ga = qkvT + (size_t)((b << 16) + (y << 8) + x) * O3 + h * 144 + kc * 8;
      else
        ga = zp;
      GLDS16(ga, &stage[ci * 8]);
    }
  }
  // zero vts K-pad cols 48..63 while staging is in flight
  if (t < 64) {
    *(uint4*)&vts[t * 72 + 48] = (uint4){0, 0, 0, 0};
    *(uint4*)&vts[t * 72 + 56] = (uint4){0, 0, 0, 0};
  }
  __syncthreads();

  // ---- dwconv 3x3: 288 tasks = (quad 0..35, py 0..7), rolling window ----
  for (int task = t; task < 288; task += 256) {
    int quad = task >> 3, py = task & 7;
    int z = quad / 12;
    if (task != t) {   // second pass (threads 0..31): reload weights
      int qc = quad - z * 12;
      int cb = z * DIMC + h * 48 + qc * 4;
#pragma unroll
      for (int cc = 0; cc < 4; ++cc)
#pragma unroll
        for (int tap = 0; tap < 9; ++tap)
          wv[tap][cc] = dwg[(size_t)(cb + cc) * 9 + tap];
    }
    const u16* sp = &stage[quad * 4];
    float L[3][4], M[3][4], R[3][4];
    float out[8][4];
    float sumsq[4] = {0.f, 0.f, 0.f, 0.f};
#pragma unroll
    for (int row = 0; row < 3; ++row) {
      ushort4 r0 = *(const ushort4*)(sp + ((py + row) * 10 + 0) * 144);
      ushort4 r1 = *(const ushort4*)(sp + ((py + row) * 10 + 1) * 144);
      L[row][0] = bf2f(r0.x); L[row][1] = bf2f(r0.y); L[row][2] = bf2f(r0.z); L[row][3] = bf2f(r0.w);
      M[row][0] = bf2f(r1.x); M[row][1] = bf2f(r1.y); M[row][2] = bf2f(r1.z); M[row][3] = bf2f(r1.w);
    }
#pragma unroll
    for (int px = 0; px < 8; ++px) {
#pragma unroll
      for (int row = 0; row < 3; ++row) {
        ushort4 rr = *(const ushort4*)(sp + ((py + row) * 10 + px + 2) * 144);
        R[row][0] = bf2f(rr.x); R[row][1] = bf2f(rr.y); R[row][2] = bf2f(rr.z); R[row][3] = bf2f(rr.w);
      }
#pragma unroll
      for (int cc = 0; cc < 4; ++cc) {
        float o = L[0][cc] * wv[0][cc] + M[0][cc] * wv[1][cc] + R[0][cc] * wv[2][cc]
                + L[1][cc] * wv[3][cc] + M[1][cc] * wv[4][cc] + R[1][cc] * wv[5][cc]
                + L[2][cc] * wv[6][cc] + M[2][cc] * wv[7][cc] + R[2][cc] * wv[8][cc];
        out[px][cc] = o;
        sumsq[cc] += o * o;
      }
#pragma unroll
      for (int row = 0; row < 3; ++row) {
#pragma unroll
        for (int cc = 0; cc < 4; ++cc) { L[row][cc] = M[row][cc]; M[row][cc] = R[row][cc]; }
      }
    }
    if (z < 2) {
      // reduce sumsq over the 8-lane py-group, scale, write q/k rows as b128
      float nrm[4];
#pragma unroll
      for (int cc = 0; cc < 4; ++cc) {
        float s = sumsq[cc];
        s += __shfl_xor(s, 1); s += __shfl_xor(s, 2); s += __shfl_xor(s, 4);
        nrm[cc] = 1.0f / fmaxf(sqrtf(s), 1e-12f);
      }
      u16* dst = (z == 0) ? qs : ks2;
      int rowb = (z == 0) ? quad * 4 : (quad - 12) * 4;
#pragma unroll
      for (int cc = 0; cc < 4; ++cc) {
        alignas(16) u16 tmp[8];
#pragma unroll
        for (int px = 0; px < 8; ++px) tmp[px] = f2bf(out[px][cc] * nrm[cc]);
        *(uint4*)&dst[(rowb + cc) * 72 + py * 8] = *(const uint4*)tmp;
      }
    } else {
      int cb = (quad - 24) * 4;
#pragma unroll
      for (int px = 0; px < 8; ++px) {
        alignas(8) u16 t4[4];
#pragma unroll
        for (int cc = 0; cc < 4; ++cc) t4[cc] = f2bf(out[px][cc]);
        *(ushort2*)&vts[(py * 8 + px) * 72 + cb]     = *(const ushort2*)&t4[0];
        *(ushort2*)&vts[(py * 8 + px) * 72 + cb + 2] = *(const ushort2*)&t4[2];
      }
    }
  }
  __syncthreads();

  // ---- S = (q_hat k_hat^T) * temp  [48x48], waves 0..2 ----
  float temp = temperature[h];
  if (wave < 3) {
    f32x4 acc3[3];
#pragma unroll
    for (int j = 0; j < 3; ++j) acc3[j] = (f32x4){0.f, 0.f, 0.f, 0.f};
#pragma unroll
    for (int ks_ = 0; ks_ < 2; ++ks_) {
      bf16x8 aq = *(const bf16x8*)&qs[(wave * 16 + lm) * 72 + ks_ * 32 + lq * 8];
#pragma unroll
      for (int j = 0; j < 3; ++j) {
        bf16x8 bk = *(const bf16x8*)&ks2[(j * 16 + lm) * 72 + ks_ * 32 + lq * 8];
        acc3[j] = __builtin_amdgcn_mfma_f32_16x16x32_bf16(aq, bk, acc3[j], 0, 0, 0);
      }
    }
#pragma unroll
    for (int j = 0; j < 3; ++j)
#pragma unroll
      for (int r = 0; r < 4; ++r)
        S[(wave * 16 + lq * 4 + r) * 52 + j * 16 + lm] = acc3[j][r] * temp;
  }
  __syncthreads();

  // ---- softmax over 48 rows; P padded to 64 cols with zeros ----
#pragma unroll
  for (int i = 0; i < 12; ++i) {
    int row = wave * 12 + i;
    float v = (lane < 48) ? S[row * 52 + lane] : -1e30f;
    float mx = v;
#pragma unroll
    for (int off = 32; off; off >>= 1) mx = fmaxf(mx, __shfl_xor(mx, off));
    float e = (lane < 48) ? __expf(v - mx) : 0.f;
    float sm = e;
#pragma unroll
    for (int off = 32; off; off >>= 1) sm += __shfl_xor(sm, off);
    Ps[row * 72 + lane] = f2bf(e / sm);
  }
  __syncthreads();

  // ---- out^T[p][c] = v^T P^T  [64x48], all 4 waves; scatter to aT ----
  {
    f32x4 accp[3];
#pragma unroll
    for (int j = 0; j < 3; ++j) accp[j] = (f32x4){0.f, 0.f, 0.f, 0.f};
#pragma unroll
    for (int ks_ = 0; ks_ < 2; ++ks_) {
      bf16x8 av = *(const bf16x8*)&vts[(wave * 16 + lm) * 72 + ks_ * 32 + lq * 8];
#pragma unroll
      for (int j = 0; j < 3; ++j) {
        bf16x8 bp = *(const bf16x8*)&Ps[(j * 16 + lm) * 72 + ks_ * 32 + lq * 8];
        accp[j] = __builtin_amdgcn_mfma_f32_16x16x32_bf16(av, bp, accp[j], 0, 0, 0);
      }
    }
#pragma unroll
    for (int j = 0; j < 3; ++j) {
#pragma unroll
      for (int r = 0; r < 4; ++r) {
        int p = wave * 16 + lq * 4 + r;
        int col = j * 16 + lm;
        int y = y0 + (p >> 3), x = x0 + (p & 7);
        size_t n = (size_t)((b << 16) + (y << 8) + x);
        aT[n * DIMC + h * 48 + col] = f2bf(accp[j][r]);
      }
    }
  }
}

// ---------------- K3: out[o][n] = wp[o][k] * aT[n][k] + bias[o]  (fp32 out) ----------------
__global__ __launch_bounds__(256, 3) void k_gemm_proj(
    const u16* __restrict__ wp, const u16* __restrict__ aT,
    const float* __restrict__ bias, float* __restrict__ out) {
  __shared__ alignas(16) u16 As[128 * 32];
  __shared__ alignas(16) u16 Bs[128 * 32];
  const int t = threadIdx.x;
  const int m0 = blockIdx.x * 128;
  const int n0 = blockIdx.y * 128;
  const int wave = t >> 6, lane = t & 63;
  const int wy = wave >> 1, wx = wave & 1;
  const int lm = lane & 15, lq = lane >> 4;

  f32x4 acc[4][4];
#pragma unroll
  for (int i = 0; i < 4; ++i)
#pragma unroll
    for (int j = 0; j < 4; ++j) acc[i][j] = (f32x4){0.f, 0.f, 0.f, 0.f};

  for (int kt = 0; kt < DIMC / 32; ++kt) {
#pragma unroll
    for (int s = 0; s < 2; ++s) {
      int ci = t + s * 256;
      int row = ci >> 2, kc = ci & 3;
      const u16* ga = wp + (size_t)(m0 + row) * DIMC + kt * 32 + kc * 8;
      const u16* gb = aT + (size_t)(n0 + row) * DIMC + kt * 32 + kc * 8;
      GLDS16(ga, &As[ci * 8]);
      GLDS16(gb, &Bs[ci * 8]);
    }
    __syncthreads();
    bf16x8 af[4], bf[4];
#pragma unroll
    for (int i = 0; i < 4; ++i) af[i] = *(const bf16x8*)&As[(wy * 64 + i * 16 + lm) * 32 + lq * 8];
#pragma unroll
    for (int j = 0; j < 4; ++j) bf[j] = *(const bf16x8*)&Bs[(wx * 64 + j * 16 + lm) * 32 + lq * 8];
#pragma unroll
    for (int i = 0; i < 4; ++i)
#pragma unroll
      for (int j = 0; j < 4; ++j)
        acc[i][j] = __builtin_amdgcn_mfma_f32_16x16x32_bf16(af[i], bf[j], acc[i][j], 0, 0, 0);
    __syncthreads();
  }
#pragma unroll
  for (int i = 0; i < 4; ++i) {
    int o_b = m0 + wy * 64 + i * 16 + lq * 4;
    float bi4[4];
#pragma unroll
    for (int r = 0; r < 4; ++r) bi4[r] = bias[o_b + r];
#pragma unroll
    for (int j = 0; j < 4; ++j) {
      int nsp = n0 + wx * 64 + j * 16 + lm;
      int b = nsp >> 16, hw = nsp & 0xFFFF;
#pragma unroll
      for (int r = 0; r < 4; ++r)
        out[(size_t)(b * DIMC + o_b + r) * HWSZ + hw] = acc[i][j][r] + bi4[r];
    }
  }
}

// ---------------- host ----------------
extern "C" void kernel_launch(void* const* d_in, const int* in_sizes, int n_in,
                              void* d_out, int out_size, void* d_ws, size_t ws_size,
                              hipStream_t stream) {
  const float* x    = (const float*)d_in[0];
  const float* qkvw = (const float*)d_in[1];
  const float* dwg  = (const float*)d_in[2];
  const float* temp = (const float*)d_in[3];
  const float* pw   = (const float*)d_in[4];
  const float* pb   = (const float*)d_in[5];
  float* out = (float*)d_out;

  char* w = (char*)d_ws;
  const size_t offXT = 0;
  const size_t offQK = offXT + (size_t)NTOT * DIMC * 2;
  const size_t offWQ = offQK + (size_t)NTOT * O3 * 2;
  const size_t offWP = offWQ + (size_t)O3 * DIMC * 2;
  const size_t offZP = offWP + (size_t)DIMC * DIMC * 2;
  const size_t need  = offZP + 256;
  if (ws_size < need) return;

  u16* xT   = (u16*)(w + offXT);
  u16* qkvT = (u16*)(w + offQK);
  u16* wq   = (u16*)(w + offWQ);
  u16* wp   = (u16*)(w + offWP);
  u16* zp   = (u16*)(w + offZP);
  u16* aT   = xT;

  k_prep<<<dim3(1728), dim3(256), 0, stream>>>(qkvw, pw, wq, wp, zp);
  k_xpose<<<dim3(1024, 6, 2), dim3(256), 0, stream>>>(x, xT);
  k_gemm_qkv<<<dim3(9, 1024), dim3(256), 0, stream>>>(xT, wq, qkvT);
  k_attn<<<dim3(2048, 8), dim3(256), 0, stream>>>(qkvT, dwg, temp, aT, zp);
  k_gemm_proj<<<dim3(3, 1024), dim3(256), 0, stream>>>(wp, aT, pb, out);
}